// Round 4
// baseline (29515.128 us; speedup 1.0000x reference)
//
#include <hip/hip_runtime.h>

#define NN 64
#define KK 16
#define HC 32   // A-columns per wave
#define HK 8    // b-columns per wave

// Broadcast a float from a (wave-uniform) lane: v_readlane -> SGPR operand.
__device__ __forceinline__ float rlane(float v, int l) {
  return __int_as_float(__builtin_amdgcn_readlane(__float_as_int(v), l));
}

// Wave64 argmax via DPP (VALU-rate). key: u32 whose order = priority.
__device__ __forceinline__ unsigned dpp_argmax64(unsigned key) {
  unsigned t;
  t = (unsigned)__builtin_amdgcn_update_dpp(0, (int)key, 0x111, 0xf, 0xf, true);
  key = key > t ? key : t;
  t = (unsigned)__builtin_amdgcn_update_dpp(0, (int)key, 0x112, 0xf, 0xf, true);
  key = key > t ? key : t;
  t = (unsigned)__builtin_amdgcn_update_dpp(0, (int)key, 0x114, 0xf, 0xf, true);
  key = key > t ? key : t;
  t = (unsigned)__builtin_amdgcn_update_dpp(0, (int)key, 0x118, 0xf, 0xf, true);
  key = key > t ? key : t;
  t = (unsigned)__builtin_amdgcn_update_dpp(0, (int)key, 0x142, 0xf, 0xf, true);
  key = key > t ? key : t;
  t = (unsigned)__builtin_amdgcn_update_dpp(0, (int)key, 0x143, 0xf, 0xf, true);
  key = key > t ? key : t;
  return (unsigned)__builtin_amdgcn_readlane((int)key, 63);
}

// 2 waves per batch (block = 128). Lane = row. Wave w owns A-columns
// {w, w+2, ..., w+62} (parity interleave -> perfectly balanced shrink) and
// b-columns [8w, 8w+8). Per-wave register state: 32+32+8+8 = 80 floats
// -> fits the 128-VGPR budget of launch_bounds(128,4): pure arch VGPRs
// (rounds 1-3 showed the 160-float single-wave variant gets split into
// AGPRs, paying accvgpr moves on every readlane/FMA), and 4 waves/SIMD.
//
// Rotation trick per wave: a wave rotates its columns left by one slot only
// on steps where it owns the current column, so the current column is always
// the owner's slot 0 and all register indices are compile-time constants.
//
// Per step: owner computes pivot p (DPP argmax) + per-row multiplier m,
// publishes {m[64], p, 1/pivot} via double-buffered LDS (buffer = step
// parity = owner id), one __syncthreads(), both waves update their columns.
// Buffer k's read (step k) and next write (step k+2) are separated by
// barrier k+1 -> race-free with a single barrier per step.
__global__ void __launch_bounds__(128, 4)
cgj_solve(const float* __restrict__ A_r, const float* __restrict__ A_i,
          const float* __restrict__ b_r, const float* __restrict__ b_i,
          float* __restrict__ out, int nbatch) {
  const int batch = blockIdx.x;
  const int w     = threadIdx.x >> 6;   // wave id: 0/1
  const int lane  = threadIdx.x & 63;   // row

  __shared__ float2 mbuf[2][64];  // per-row multiplier, double-buffered
  __shared__ float4 hdr[2];       // {ip_re, ip_im, bits(p), 0}

  float Cr[HC], Ci[HC], Br[HK], Bi[HK];

  // ---- load: lane reads its full row, keeps parity-w columns ----
  const size_t abase = (size_t)batch * NN * NN + (size_t)lane * NN;
  const float4* pAr = reinterpret_cast<const float4*>(A_r + abase);
  const float4* pAi = reinterpret_cast<const float4*>(A_i + abase);
#pragma unroll
  for (int j = 0; j < 16; ++j) {
    float4 v = pAr[j];                  // cols 4j .. 4j+3
    Cr[2*j]   = w ? v.y : v.x;
    Cr[2*j+1] = w ? v.w : v.z;
  }
#pragma unroll
  for (int j = 0; j < 16; ++j) {
    float4 v = pAi[j];
    Ci[2*j]   = w ? v.y : v.x;
    Ci[2*j+1] = w ? v.w : v.z;
  }
  const size_t bbase = (size_t)batch * NN * KK + (size_t)lane * KK + (size_t)(HK * w);
  const float4* pbr = reinterpret_cast<const float4*>(b_r + bbase);
  const float4* pbi = reinterpret_cast<const float4*>(b_i + bbase);
#pragma unroll
  for (int j = 0; j < HK / 4; ++j) {
    float4 v = pbr[j];
    Br[4*j+0] = v.x; Br[4*j+1] = v.y; Br[4*j+2] = v.z; Br[4*j+3] = v.w;
    float4 u = pbi[j];
    Bi[4*j+0] = u.x; Bi[4*j+1] = u.y; Bi[4*j+2] = u.z; Bi[4*j+3] = u.w;
  }

  float invd_re = 0.f, invd_im = 0.f;
  int   mystep  = 0;
  bool  done    = false;

  for (int k = 0; k < NN; ++k) {
    const int owner = k & 1;
    float m_re, m_im;
    int   p;

    if (w == owner) {
      // ---- pivot: DPP argmax of |slot0|^2, lane idx in low 6 bits ----
      const float sc = Cr[0]*Cr[0] + Ci[0]*Ci[0];
      unsigned key = done ? (unsigned)lane
                          : ((__float_as_uint(sc) & ~63u) | (unsigned)lane);
      p = (int)(dpp_argmax64(key) & 63u);
      const float p_re = rlane(Cr[0], p);
      const float p_im = rlane(Ci[0], p);
      const float d    = p_re*p_re + p_im*p_im;
      float rd = __builtin_amdgcn_rcpf(d);
      rd = rd * (2.0f - d * rd);
      const float ip_re =  p_re * rd;
      const float ip_im = -p_im * rd;
      m_re = Cr[0]*ip_re - Ci[0]*ip_im;
      m_im = Cr[0]*ip_im + Ci[0]*ip_re;
      if (lane == p) {
        m_re = 0.f; m_im = 0.f;
        invd_re = ip_re; invd_im = ip_im;
        mystep = k; done = true;
      }
      mbuf[owner][lane] = float2{m_re, m_im};
      if (lane == 0)
        hdr[owner] = float4{ip_re, ip_im, __uint_as_float((unsigned)p), 0.f};
    }
    __syncthreads();
    if (w != owner) {
      const float2 mv = mbuf[owner][lane];
      const float4 h  = hdr[owner];
      m_re = mv.x; m_im = mv.y;
      p = __builtin_amdgcn_readfirstlane(__float_as_int(h.z));
      if (lane == p) {
        invd_re = h.x; invd_im = h.y;
        mystep = k; done = true;
      }
    }

    // ---- A update (own columns, static indices, 8-block dead skipping) ----
    if (w == owner) {
      // live slots 0..(31 - k/2); eliminate slot 0, rotate 1..hi -> 0..hi-1
      const int hi = 31 - (k >> 1);
#pragma unroll
      for (int blk = 0; blk < 4; ++blk) {
        const int j0 = (blk == 0) ? 1 : 8 * blk;
        if (hi >= j0) {
#pragma unroll
          for (int j = j0; j < 8 * (blk + 1); ++j) {
            const float sr = rlane(Cr[j], p);
            const float si = rlane(Ci[j], p);
            Cr[j-1] = __builtin_fmaf(-m_re, sr, __builtin_fmaf( m_im, si, Cr[j]));
            Ci[j-1] = __builtin_fmaf(-m_im, sr, __builtin_fmaf(-m_re, si, Ci[j]));
          }
        }
      }
    } else {
      // live slots 0..(31 - (k+1)/2), update in place
      const int hi = 31 - ((k + 1) >> 1);
#pragma unroll
      for (int blk = 0; blk < 4; ++blk) {
        if (hi >= 8 * blk) {
#pragma unroll
          for (int j = 8 * blk; j < 8 * (blk + 1); ++j) {
            const float sr = rlane(Cr[j], p);
            const float si = rlane(Ci[j], p);
            Cr[j] = __builtin_fmaf(-m_re, sr, __builtin_fmaf( m_im, si, Cr[j]));
            Ci[j] = __builtin_fmaf(-m_im, sr, __builtin_fmaf(-m_re, si, Ci[j]));
          }
        }
      }
    }

    // ---- b update (own 8 columns, both waves) ----
#pragma unroll
    for (int c = 0; c < HK; ++c) {
      const float sr = rlane(Br[c], p);
      const float si = rlane(Bi[c], p);
      Br[c] = __builtin_fmaf(-m_re, sr, __builtin_fmaf( m_im, si, Br[c]));
      Bi[c] = __builtin_fmaf(-m_im, sr, __builtin_fmaf(-m_re, si, Bi[c]));
    }
  }

  // ---- x[mystep][c] = b[c] * invd ; lane writes its row, own 8 columns ----
  float xr[HK], xi[HK];
#pragma unroll
  for (int c = 0; c < HK; ++c) {
    xr[c] = Br[c]*invd_re - Bi[c]*invd_im;
    xi[c] = Br[c]*invd_im + Bi[c]*invd_re;
  }
  const size_t obase = (size_t)batch * NN * KK + (size_t)mystep * KK + (size_t)(HK * w);
  float* o_r = out + obase;
  float* o_i = out + (size_t)nbatch * NN * KK + obase;
#pragma unroll
  for (int j = 0; j < HK / 4; ++j) {
    float4 v;
    v.x = xr[4*j+0]; v.y = xr[4*j+1]; v.z = xr[4*j+2]; v.w = xr[4*j+3];
    reinterpret_cast<float4*>(o_r)[j] = v;
    float4 u;
    u.x = xi[4*j+0]; u.y = xi[4*j+1]; u.z = xi[4*j+2]; u.w = xi[4*j+3];
    reinterpret_cast<float4*>(o_i)[j] = u;
  }
}

extern "C" void kernel_launch(void* const* d_in, const int* in_sizes, int n_in,
                              void* d_out, int out_size, void* d_ws, size_t ws_size,
                              hipStream_t stream) {
  const float* A_r = (const float*)d_in[0];
  const float* A_i = (const float*)d_in[1];
  const float* b_r = (const float*)d_in[2];
  const float* b_i = (const float*)d_in[3];
  float* out = (float*)d_out;
  const int nbatch = in_sizes[0] / (NN * NN);  // 8192
  cgj_solve<<<nbatch, 128, 0, stream>>>(A_r, A_i, b_r, b_i, out, nbatch);
}

// Round 5
// 1566.998 us; speedup vs baseline: 18.8355x; 18.8355x over previous
//
#include <hip/hip_runtime.h>

#define NN 64
#define KK 16
#define HC 32   // A-columns per wave
#define HK 8    // b-columns per wave

// Broadcast a float from a (wave-uniform) lane: v_readlane -> SGPR operand.
__device__ __forceinline__ float rlane(float v, int l) {
  return __int_as_float(__builtin_amdgcn_readlane(__float_as_int(v), l));
}

// Wave64 argmax via DPP (VALU-rate). key: u32 whose order = priority.
__device__ __forceinline__ unsigned dpp_argmax64(unsigned key) {
  unsigned t;
  t = (unsigned)__builtin_amdgcn_update_dpp(0, (int)key, 0x111, 0xf, 0xf, true);
  key = key > t ? key : t;
  t = (unsigned)__builtin_amdgcn_update_dpp(0, (int)key, 0x112, 0xf, 0xf, true);
  key = key > t ? key : t;
  t = (unsigned)__builtin_amdgcn_update_dpp(0, (int)key, 0x114, 0xf, 0xf, true);
  key = key > t ? key : t;
  t = (unsigned)__builtin_amdgcn_update_dpp(0, (int)key, 0x118, 0xf, 0xf, true);
  key = key > t ? key : t;
  t = (unsigned)__builtin_amdgcn_update_dpp(0, (int)key, 0x142, 0xf, 0xf, true);
  key = key > t ? key : t;
  t = (unsigned)__builtin_amdgcn_update_dpp(0, (int)key, 0x143, 0xf, 0xf, true);
  key = key > t ? key : t;
  return (unsigned)__builtin_amdgcn_readlane((int)key, 63);
}

// 2 waves per batch (block = 128). Lane = row. Wave w owns A-columns
// {w, w+2, ..., w+62} (parity interleave -> balanced shrink) and b-columns
// [8w, 8w+8). Per-wave register state: 80 floats + temps (~130 regs).
//
// launch_bounds(128,2): 256-reg cap. Round-4 evidence: the (128,4) hard
// 128-reg promise made the allocator spill the arrays to scratch (100 GB of
// scratch writes, VALUBusy 2%). With 256 of slack the ~130-reg allocation
// fits; occupancy is then set by actual usage (3-4 waves/SIMD).
//
// p is re-uniformed with readfirstlane AFTER the owner/non-owner merge:
// `w == owner` is divergent to the compiler, so the merged p would otherwise
// be a divergent value and every readlane(C[j], p) would waterfall.
//
// Rotation trick per wave: a wave rotates its columns left by one slot only
// on steps where it owns the current column, so the current column is always
// the owner's slot 0 and all register indices are compile-time constants.
//
// Per step: owner computes pivot p (DPP argmax) + per-row multiplier m,
// publishes {m[64], p, 1/pivot} via double-buffered LDS (buffer = step
// parity), one __syncthreads(), both waves update their own columns.
// Read@k and the next write@k+2 of the same buffer are separated by
// barrier@k+1 -> race-free with a single barrier per step.
__global__ void __launch_bounds__(128, 2)
cgj_solve(const float* __restrict__ A_r, const float* __restrict__ A_i,
          const float* __restrict__ b_r, const float* __restrict__ b_i,
          float* __restrict__ out, int nbatch) {
  const int batch = blockIdx.x;
  const int w     = threadIdx.x >> 6;   // wave id: 0/1
  const int lane  = threadIdx.x & 63;   // row

  __shared__ float2 mbuf[2][64];  // per-row multiplier, double-buffered
  __shared__ float4 hdr[2];       // {ip_re, ip_im, bits(p), 0}

  float Cr[HC], Ci[HC], Br[HK], Bi[HK];

  // ---- load: lane reads its full row, keeps parity-w columns ----
  const size_t abase = (size_t)batch * NN * NN + (size_t)lane * NN;
  const float4* pAr = reinterpret_cast<const float4*>(A_r + abase);
  const float4* pAi = reinterpret_cast<const float4*>(A_i + abase);
#pragma unroll
  for (int j = 0; j < 16; ++j) {
    float4 v = pAr[j];                  // cols 4j .. 4j+3
    Cr[2*j]   = w ? v.y : v.x;
    Cr[2*j+1] = w ? v.w : v.z;
  }
#pragma unroll
  for (int j = 0; j < 16; ++j) {
    float4 v = pAi[j];
    Ci[2*j]   = w ? v.y : v.x;
    Ci[2*j+1] = w ? v.w : v.z;
  }
  const size_t bbase = (size_t)batch * NN * KK + (size_t)lane * KK + (size_t)(HK * w);
  const float4* pbr = reinterpret_cast<const float4*>(b_r + bbase);
  const float4* pbi = reinterpret_cast<const float4*>(b_i + bbase);
#pragma unroll
  for (int j = 0; j < HK / 4; ++j) {
    float4 v = pbr[j];
    Br[4*j+0] = v.x; Br[4*j+1] = v.y; Br[4*j+2] = v.z; Br[4*j+3] = v.w;
    float4 u = pbi[j];
    Bi[4*j+0] = u.x; Bi[4*j+1] = u.y; Bi[4*j+2] = u.z; Bi[4*j+3] = u.w;
  }

  float invd_re = 0.f, invd_im = 0.f;
  int   mystep  = 0;
  bool  done    = false;

  for (int k = 0; k < NN; ++k) {
    const int owner = k & 1;
    float m_re, m_im;
    int   p_loc;

    if (w == owner) {
      // ---- pivot: DPP argmax of |slot0|^2, lane idx in low 6 bits ----
      const float sc = Cr[0]*Cr[0] + Ci[0]*Ci[0];
      unsigned key = done ? (unsigned)lane
                          : ((__float_as_uint(sc) & ~63u) | (unsigned)lane);
      const int p = (int)(dpp_argmax64(key) & 63u);
      const float p_re = rlane(Cr[0], p);
      const float p_im = rlane(Ci[0], p);
      const float d    = p_re*p_re + p_im*p_im;
      float rd = __builtin_amdgcn_rcpf(d);
      rd = rd * (2.0f - d * rd);
      const float ip_re =  p_re * rd;
      const float ip_im = -p_im * rd;
      m_re = Cr[0]*ip_re - Ci[0]*ip_im;
      m_im = Cr[0]*ip_im + Ci[0]*ip_re;
      if (lane == p) {
        m_re = 0.f; m_im = 0.f;
        invd_re = ip_re; invd_im = ip_im;
        mystep = k; done = true;
      }
      mbuf[owner][lane] = float2{m_re, m_im};
      if (lane == 0)
        hdr[owner] = float4{ip_re, ip_im, __uint_as_float((unsigned)p), 0.f};
      p_loc = p;
    }
    __syncthreads();
    if (w != owner) {
      const float2 mv = mbuf[owner][lane];
      const float4 h  = hdr[owner];
      m_re = mv.x; m_im = mv.y;
      p_loc = (int)__float_as_uint(h.z);
      if (lane == p_loc) {
        invd_re = h.x; invd_im = h.y;
        mystep = k; done = true;
      }
    }
    // Re-uniform p: the w==owner branch is divergent to the compiler, so the
    // merged value would otherwise be divergent -> readlane waterfalls.
    const int p = __builtin_amdgcn_readfirstlane(p_loc);

    // ---- A update (own columns, static indices, 8-block dead skipping) ----
    if (w == owner) {
      // live slots 0..(31 - k/2); eliminate slot 0, rotate 1..hi -> 0..hi-1
      const int hi = 31 - (k >> 1);
#pragma unroll
      for (int blk = 0; blk < 4; ++blk) {
        const int j0 = (blk == 0) ? 1 : 8 * blk;
        if (hi >= j0) {
#pragma unroll
          for (int j = j0; j < 8 * (blk + 1); ++j) {
            const float sr = rlane(Cr[j], p);
            const float si = rlane(Ci[j], p);
            Cr[j-1] = __builtin_fmaf(-m_re, sr, __builtin_fmaf( m_im, si, Cr[j]));
            Ci[j-1] = __builtin_fmaf(-m_im, sr, __builtin_fmaf(-m_re, si, Ci[j]));
          }
        }
      }
    } else {
      // live slots 0..(31 - (k+1)/2), update in place
      const int hi = 31 - ((k + 1) >> 1);
#pragma unroll
      for (int blk = 0; blk < 4; ++blk) {
        if (hi >= 8 * blk) {
#pragma unroll
          for (int j = 8 * blk; j < 8 * (blk + 1); ++j) {
            const float sr = rlane(Cr[j], p);
            const float si = rlane(Ci[j], p);
            Cr[j] = __builtin_fmaf(-m_re, sr, __builtin_fmaf( m_im, si, Cr[j]));
            Ci[j] = __builtin_fmaf(-m_im, sr, __builtin_fmaf(-m_re, si, Ci[j]));
          }
        }
      }
    }

    // ---- b update (own 8 columns, both waves) ----
#pragma unroll
    for (int c = 0; c < HK; ++c) {
      const float sr = rlane(Br[c], p);
      const float si = rlane(Bi[c], p);
      Br[c] = __builtin_fmaf(-m_re, sr, __builtin_fmaf( m_im, si, Br[c]));
      Bi[c] = __builtin_fmaf(-m_im, sr, __builtin_fmaf(-m_re, si, Bi[c]));
    }
  }

  // ---- x[mystep][c] = b[c] * invd ; lane writes its row, own 8 columns ----
  float xr[HK], xi[HK];
#pragma unroll
  for (int c = 0; c < HK; ++c) {
    xr[c] = Br[c]*invd_re - Bi[c]*invd_im;
    xi[c] = Br[c]*invd_im + Bi[c]*invd_re;
  }
  const size_t obase = (size_t)batch * NN * KK + (size_t)mystep * KK + (size_t)(HK * w);
  float* o_r = out + obase;
  float* o_i = out + (size_t)nbatch * NN * KK + obase;
#pragma unroll
  for (int j = 0; j < HK / 4; ++j) {
    float4 v;
    v.x = xr[4*j+0]; v.y = xr[4*j+1]; v.z = xr[4*j+2]; v.w = xr[4*j+3];
    reinterpret_cast<float4*>(o_r)[j] = v;
    float4 u;
    u.x = xi[4*j+0]; u.y = xi[4*j+1]; u.z = xi[4*j+2]; u.w = xi[4*j+3];
    reinterpret_cast<float4*>(o_i)[j] = u;
  }
}

extern "C" void kernel_launch(void* const* d_in, const int* in_sizes, int n_in,
                              void* d_out, int out_size, void* d_ws, size_t ws_size,
                              hipStream_t stream) {
  const float* A_r = (const float*)d_in[0];
  const float* A_i = (const float*)d_in[1];
  const float* b_r = (const float*)d_in[2];
  const float* b_i = (const float*)d_in[3];
  float* out = (float*)d_out;
  const int nbatch = in_sizes[0] / (NN * NN);  // 8192
  cgj_solve<<<nbatch, 128, 0, stream>>>(A_r, A_i, b_r, b_i, out, nbatch);
}

// Round 7
// 500.976 us; speedup vs baseline: 58.9153x; 3.1279x over previous
//
#include <hip/hip_runtime.h>

#define NN 64
#define KK 16

// Broadcast a float from a (wave-uniform) lane: v_readlane -> SGPR operand.
__device__ __forceinline__ float rlane(float v, int l) {
  return __int_as_float(__builtin_amdgcn_readlane(__float_as_int(v), l));
}

// Wave64 argmax via DPP (VALU-rate, no LDS-pipe shuffles).
// key must be a u32 whose integer order matches the desired priority.
// Returns the max key over all 64 lanes (uniform via readlane 63).
__device__ __forceinline__ unsigned dpp_argmax64(unsigned key) {
  unsigned t;
  // row_shr:1,2,4,8 within each row of 16
  t = (unsigned)__builtin_amdgcn_update_dpp(0, (int)key, 0x111, 0xf, 0xf, true);
  key = key > t ? key : t;
  t = (unsigned)__builtin_amdgcn_update_dpp(0, (int)key, 0x112, 0xf, 0xf, true);
  key = key > t ? key : t;
  t = (unsigned)__builtin_amdgcn_update_dpp(0, (int)key, 0x114, 0xf, 0xf, true);
  key = key > t ? key : t;
  t = (unsigned)__builtin_amdgcn_update_dpp(0, (int)key, 0x118, 0xf, 0xf, true);
  key = key > t ? key : t;
  // row_bcast15: lane15 -> lanes 16..31, lane47 -> lanes 48..63
  t = (unsigned)__builtin_amdgcn_update_dpp(0, (int)key, 0x142, 0xf, 0xf, true);
  key = key > t ? key : t;
  // row_bcast31: lane31 -> lanes 32..63
  t = (unsigned)__builtin_amdgcn_update_dpp(0, (int)key, 0x143, 0xf, 0xf, true);
  key = key > t ? key : t;
  // global max now in lane 63
  return (unsigned)__builtin_amdgcn_readlane((int)key, 63);
}

// One wave per batch. Lane i owns row i of the augmented complex system [A | b]
// in registers: Cr/Ci[64], Br/Bi[16]. Gauss-Jordan with partial pivoting.
// (Identical algorithm to the passing round-3 kernel.)
//
// amdgpu_waves_per_eu(1,1): THE fix this round. launch_bounds' 2nd arg is a
// MIN-waves promise, so in rounds 1-3 the allocator still targeted its
// default occupancy, overflowed the arch budget, and spilled the 160-float
// row state to AGPRs (VGPR_Count=96 + ~160 AGPR) -- every readlane/DPP then
// paid v_accvgpr_read/write moves (~54k VALU instr/wave vs ~23k algorithmic).
// Capping max waves/EU at 1 gives a 512-reg unified budget; the ~220-reg
// peak fits entirely in arch VGPRs -> no AGPR spill, no move tax. A single
// wave64 can still saturate the SIMD VALU (1 instr/cy issue, 2 cy/VALU-op,
// ample ILP across independent columns), and steady-state memory traffic
// is nil, so 1 wave/SIMD occupancy is sufficient.
//
// Rotation trick: each elimination step shifts the A-part left by one slot
// (folded into the update FMA), so the current pivot column is ALWAYS index 0
// -> all register indices are compile-time constants.
__global__ void __launch_bounds__(64)
__attribute__((amdgpu_waves_per_eu(1, 1)))
cgj_solve(const float* __restrict__ A_r, const float* __restrict__ A_i,
          const float* __restrict__ b_r, const float* __restrict__ b_i,
          float* __restrict__ out, int nbatch) {
  const int batch = blockIdx.x;
  const int lane  = threadIdx.x;

  float Cr[NN], Ci[NN], Br[KK], Bi[KK];

  // ---- load: lane i reads its full row (float4-vectorized) ----
  const size_t abase = (size_t)batch * NN * NN + (size_t)lane * NN;
  const float4* pAr = reinterpret_cast<const float4*>(A_r + abase);
  const float4* pAi = reinterpret_cast<const float4*>(A_i + abase);
#pragma unroll
  for (int j = 0; j < NN / 4; ++j) {
    float4 v = pAr[j];
    Cr[4*j+0] = v.x; Cr[4*j+1] = v.y; Cr[4*j+2] = v.z; Cr[4*j+3] = v.w;
  }
#pragma unroll
  for (int j = 0; j < NN / 4; ++j) {
    float4 v = pAi[j];
    Ci[4*j+0] = v.x; Ci[4*j+1] = v.y; Ci[4*j+2] = v.z; Ci[4*j+3] = v.w;
  }
  const size_t bbase = (size_t)batch * NN * KK + (size_t)lane * KK;
  const float4* pbr = reinterpret_cast<const float4*>(b_r + bbase);
  const float4* pbi = reinterpret_cast<const float4*>(b_i + bbase);
#pragma unroll
  for (int j = 0; j < KK / 4; ++j) {
    float4 v = pbr[j];
    Br[4*j+0] = v.x; Br[4*j+1] = v.y; Br[4*j+2] = v.z; Br[4*j+3] = v.w;
  }
#pragma unroll
  for (int j = 0; j < KK / 4; ++j) {
    float4 v = pbi[j];
    Bi[4*j+0] = v.x; Bi[4*j+1] = v.y; Bi[4*j+2] = v.z; Bi[4*j+3] = v.w;
  }

  float invd_re = 0.f, invd_im = 0.f;
  int   mystep  = 0;
  bool  done    = false;

  for (int k = 0; k < NN; ++k) {
    // ---- partial pivot: DPP argmax of |C[0]|^2, lane idx in low 6 bits ----
    const float sc = Cr[0]*Cr[0] + Ci[0]*Ci[0];            // >= 0
    unsigned key = done ? (unsigned)lane
                        : ((__float_as_uint(sc) & ~63u) | (unsigned)lane);
    const unsigned kmax = dpp_argmax64(key);
    const int p = (int)(kmax & 63u);

    // ---- pivot value and its complex reciprocal (wave-uniform) ----
    const float p_re = rlane(Cr[0], p);
    const float p_im = rlane(Ci[0], p);
    const float d    = p_re*p_re + p_im*p_im;
    float rd = __builtin_amdgcn_rcpf(d);
    rd = rd * (2.0f - d * rd);                              // 1 Newton step
    const float ip_re =  p_re * rd;
    const float ip_im = -p_im * rd;

    // ---- per-lane multiplier m = C[0] * inv(pivot); pivot row: m = 0 ----
    float m_re = Cr[0]*ip_re - Ci[0]*ip_im;
    float m_im = Cr[0]*ip_im + Ci[0]*ip_re;
    if (lane == p) {
      m_re = 0.f; m_im = 0.f;
      invd_re = ip_re; invd_im = ip_im;
      mystep = k; done = true;
    }

    // ---- A part: rotate-left-by-1 fused with elimination update ----
    // Live columns occupy slots [0 .. 63-k]; skip fully-dead 8-blocks
    // (wave-uniform branch).
#pragma unroll
    for (int blk = 0; blk < 8; ++blk) {
      if (63 - k >= 8 * blk) {
        const int j0 = (blk == 0) ? 1 : 8 * blk;
#pragma unroll
        for (int j = j0; j < 8 * (blk + 1); ++j) {
          const float sr = rlane(Cr[j], p);
          const float si = rlane(Ci[j], p);
          // Cr' = Cr - m_re*sr + m_im*si ; Ci' = Ci - m_re*si - m_im*sr
          Cr[j-1] = __builtin_fmaf(-m_re, sr, __builtin_fmaf( m_im, si, Cr[j]));
          Ci[j-1] = __builtin_fmaf(-m_im, sr, __builtin_fmaf(-m_re, si, Ci[j]));
        }
      }
    }

    // ---- b part (fixed positions, no rotation) ----
#pragma unroll
    for (int c = 0; c < KK; ++c) {
      const float sr = rlane(Br[c], p);
      const float si = rlane(Bi[c], p);
      Br[c] = __builtin_fmaf(-m_re, sr, __builtin_fmaf( m_im, si, Br[c]));
      Bi[c] = __builtin_fmaf(-m_im, sr, __builtin_fmaf(-m_re, si, Bi[c]));
    }
  }

  // ---- x[mystep][c] = b[c] * invd ; each lane writes its solution row ----
  float xr[KK], xi[KK];
#pragma unroll
  for (int c = 0; c < KK; ++c) {
    xr[c] = Br[c]*invd_re - Bi[c]*invd_im;
    xi[c] = Br[c]*invd_im + Bi[c]*invd_re;
  }
  const size_t obase = (size_t)batch * NN * KK + (size_t)mystep * KK;
  float* o_r = out + obase;
  float* o_i = out + (size_t)nbatch * NN * KK + obase;
#pragma unroll
  for (int j = 0; j < KK / 4; ++j) {
    float4 v;
    v.x = xr[4*j+0]; v.y = xr[4*j+1]; v.z = xr[4*j+2]; v.w = xr[4*j+3];
    reinterpret_cast<float4*>(o_r)[j] = v;
    float4 w;
    w.x = xi[4*j+0]; w.y = xi[4*j+1]; w.z = xi[4*j+2]; w.w = xi[4*j+3];
    reinterpret_cast<float4*>(o_i)[j] = w;
  }
}

extern "C" void kernel_launch(void* const* d_in, const int* in_sizes, int n_in,
                              void* d_out, int out_size, void* d_ws, size_t ws_size,
                              hipStream_t stream) {
  const float* A_r = (const float*)d_in[0];
  const float* A_i = (const float*)d_in[1];
  const float* b_r = (const float*)d_in[2];
  const float* b_i = (const float*)d_in[3];
  float* out = (float*)d_out;
  const int nbatch = in_sizes[0] / (NN * NN);  // 8192
  cgj_solve<<<nbatch, 64, 0, stream>>>(A_r, A_i, b_r, b_i, out, nbatch);
}